// Round 5
// baseline (159.604 us; speedup 1.0000x reference)
//
#include <hip/hip_runtime.h>
#include <math.h>

#define NQ    8192
#define NPTS  32768
#define KNN   64
#define GRIDD 16
#define NCELL 4096          // 16^3 cells, h=0.5 over [-4,4)
#define CAP   224           // per-query candidate capacity (E=110, sigma~10)

// ---- ws layout (4B elements) ----
#define WS_CNT   0          // 4096  count -> cursor
#define WS_START 4096       // 4097  cell start offsets
#define WS_TAU   8704       // 8192  per-query tau (d^2 radius)
#define WS_X     16896      // 32768 reordered x
#define WS_Y     49664
#define WS_Z     82432
#define WS_I     115200     // 32768 original indices
#define WS_TOTAL 147968     // elements (~592 KB)

__device__ __forceinline__ int mbcnt64(unsigned long long m) {
  return __builtin_amdgcn_mbcnt_hi((unsigned)(m >> 32),
         __builtin_amdgcn_mbcnt_lo((unsigned)m, 0));
}
__device__ __forceinline__ int cell1(float v) {
  int c = (int)floorf((v + 4.f) * 2.f);
  return min(GRIDD - 1, max(0, c));
}
__device__ __forceinline__ float norm_cdf(float x) { return 0.5f * erfcf(-x * 0.70710678f); }
// Mass of standard 3D gaussian inside ball radius r centered at distance mu (exact).
__device__ __forceinline__ float ball_mass(float mu, float r) {
  float a = r - mu, b = r + mu;
  float e = __expf(-0.5f * b * b) - __expf(-0.5f * a * a);
  return e / (mu * 2.50662827f) + norm_cdf(a) - norm_cdf(-mu) + norm_cdf(b) - norm_cdf(mu);
}

// ============ K1: per-query tau (blocks 0..31) + cell counts (blocks 32..159) ============
__global__ void k_count_tau(const float* __restrict__ qpos, const float* __restrict__ pos,
                            int* __restrict__ cnt, float* __restrict__ tau) {
  const int b = blockIdx.x;
  if (b < 32) {
    const int q = b * 256 + threadIdx.x;
    float x = qpos[3 * q], y = qpos[3 * q + 1], z = qpos[3 * q + 2];
    float b2 = x * x + y * y + z * z;
    float mu = fmaxf(sqrtf(b2), 0.05f);
    const float target = 110.0f / 32768.0f;   // E[candidates] = 110
    float lo = 0.f, hi = mu + 8.f;
    for (int i = 0; i < 20; ++i) {
      float r = 0.5f * (lo + hi);
      if (ball_mass(mu, r) < target) lo = r; else hi = r;
    }
    tau[q] = hi * hi;
  } else {
    const int p = (b - 32) * 256 + threadIdx.x;
    float x = pos[3 * p], y = pos[3 * p + 1], z = pos[3 * p + 2];
    int c = (cell1(z) * GRIDD + cell1(y)) * GRIDD + cell1(x);
    atomicAdd(&cnt[c], 1);
  }
}

// ============ K2: exclusive scan of 4096 counts (1 block); cursor = cnt (overwritten) ======
__global__ void k_scan(int* __restrict__ cnt, int* __restrict__ start) {
  __shared__ int wsum[4];
  const int tid = threadIdx.x, lane = tid & 63, wv = tid >> 6;
  int loc[16]; int s = 0;
  #pragma unroll
  for (int i = 0; i < 16; ++i) { loc[i] = cnt[tid * 16 + i]; s += loc[i]; }
  int sc = s;                               // wave inclusive scan
  #pragma unroll
  for (int d = 1; d < 64; d <<= 1) { int t = __shfl_up(sc, d, 64); if (lane >= d) sc += t; }
  if (lane == 63) wsum[wv] = sc;
  __syncthreads();
  int wpre = 0;
  for (int w = 0; w < wv; ++w) wpre += wsum[w];
  int excl = wpre + sc - s;
  #pragma unroll
  for (int i = 0; i < 16; ++i) { start[tid * 16 + i] = excl; cnt[tid * 16 + i] = excl; excl += loc[i]; }
  if (tid == 255) start[NCELL] = excl;      // = 32768
}

// ============ K3: scatter points into cell-sorted SoA + original index ============
__global__ void k_scatter(const float* __restrict__ pos, int* __restrict__ cursor,
                          float* __restrict__ X, float* __restrict__ Y, float* __restrict__ Z,
                          int* __restrict__ I) {
  const int p = blockIdx.x * 256 + threadIdx.x;
  float x = pos[3 * p], y = pos[3 * p + 1], z = pos[3 * p + 2];
  int c = (cell1(z) * GRIDD + cell1(y)) * GRIDD + cell1(x);
  int j = atomicAdd(&cursor[c], 1);
  X[j] = x; Y[j] = y; Z[j] = z; I[j] = p;
}

// ============ K4: main — one wave per query, no block barriers ============
__global__ __launch_bounds__(256, 8) void k_main(
    const float* __restrict__ qpos, const float* __restrict__ feat,
    const float* __restrict__ tauA, const int* __restrict__ start,
    const float* __restrict__ X, const float* __restrict__ Y, const float* __restrict__ Z,
    const int* __restrict__ I, float* __restrict__ out) {

  __shared__ uint2 sCand[4][CAP];   // per-wave private regions; no __syncthreads needed
  __shared__ uint2 sSel[4][KNN];

  const int tid = threadIdx.x, lane = tid & 63, wv = tid >> 6;
  const int gq  = blockIdx.x * 4 + wv;

  const float qx = qpos[3 * gq], qy = qpos[3 * gq + 1], qz = qpos[3 * gq + 2];
  float tau = tauA[gq];
  float tlo = 0.f, thi = -1.f;      // bisection bounds for tau retries (-1 = none)
  int m = 0;

  // ---- candidate collection: scan cells overlapping ball(q, sqrt(tau)) ----
  for (int attempt = 0; attempt < 16; ++attempt) {
    m = 0;
    const float r = sqrtf(tau);
    const int xlo = cell1(qx - r), xhi = cell1(qx + r);
    const int ylo = cell1(qy - r), yhi = cell1(qy + r);
    const int zlo = cell1(qz - r), zhi = cell1(qz + r);
    for (int cz = zlo; cz <= zhi; ++cz) {
      for (int cy = ylo; cy <= yhi; ++cy) {
        const int row = (cz * GRIDD + cy) * GRIDD;
        const int rs = start[row + xlo];
        const int re = start[row + xhi + 1];   // x-cells contiguous -> one run per row
        for (int j0 = rs; j0 < re; j0 += 64) {
          const int j = j0 + lane;
          float d = 3.4e38f;
          if (j < re) {
            float dx = X[j] - qx, dy = Y[j] - qy, dz = Z[j] - qz;
            d = fmaf(dx, dx, fmaf(dy, dy, dz * dz));   // >= 0, bits monotone
          }
          const bool h = d < tau;
          const unsigned long long msk = __ballot(h);
          if (msk) {
            const int p = m + mbcnt64(msk);
            if (h && p < CAP) sCand[wv][p] = make_uint2(__float_as_uint(d), (unsigned)I[j]);
            m += (int)__popcll(msk);
          }
        }
      }
    }
    if (m >= KNN && m <= CAP) break;
    if (m < KNN) { tlo = tau; tau = (thi < 0.f) ? tau * 2.5f : 0.5f * (tau + thi); }
    else         { thi = tau; tau = 0.5f * (tlo + tau); }
  }

  // ---- exact top-64: bisection on raw float bits (nonneg -> order-preserving) ----
  const int mm = min(m, CAP);
  const int NS = (mm + 63) >> 6;     // slots actually populated (typ. 2)
  unsigned k[4], id[4];
  #pragma unroll
  for (int s = 0; s < 4; ++s) {
    k[s] = 0xFFFFFFFFu; id[s] = 0u;
    if (s < NS) {
      const int g = s * 64 + lane;
      if (g < mm) { uint2 kv = sCand[wv][g]; k[s] = kv.x; id[s] = kv.y; }
    }
  }
  sSel[wv][lane] = make_uint2(0u, 0u);   // safety padding (w=0)

  if (mm > KNN) {
    unsigned lo = 0u, hi = __float_as_uint(tau);
    while (lo < hi) {
      const unsigned mid = lo + ((hi - lo) >> 1);
      int c = 0;
      #pragma unroll
      for (int s = 0; s < 4; ++s)
        if (s < NS) c += (int)__popcll(__ballot(k[s] <= mid));
      if (c >= KNN) hi = mid; else lo = mid + 1;
    }
    const unsigned K = lo;   // 64th-smallest key
    int fill = 0;
    #pragma unroll
    for (int s = 0; s < 4; ++s) {
      if (s < NS) {
        const bool lt = k[s] < K;
        const unsigned long long msk = __ballot(lt);
        if (msk) {
          const int p = fill + mbcnt64(msk);
          if (lt) {
            float dv = __uint_as_float(k[s]);
            float w_ = 1.f / (sqrtf(fmaxf(dv, 1e-12f)) + 1e-5f);
            sSel[wv][p] = make_uint2(id[s], __float_as_uint(w_));
          }
          fill += (int)__popcll(msk);
        }
      }
    }
    #pragma unroll
    for (int s = 0; s < 4; ++s) {      // ties at K fill remaining slots
      if (s < NS) {
        const bool eq = (k[s] == K);
        const unsigned long long msk = __ballot(eq);
        if (msk) {
          const int p = fill + mbcnt64(msk);
          if (eq && p < KNN) {
            float dv = __uint_as_float(k[s]);
            float w_ = 1.f / (sqrtf(fmaxf(dv, 1e-12f)) + 1e-5f);
            sSel[wv][p] = make_uint2(id[s], __float_as_uint(w_));
          }
          fill += (int)__popcll(msk);
        }
      }
    }
  } else {                             // mm <= 64: take all
    #pragma unroll
    for (int s = 0; s < 4; ++s) {
      if (s < NS) {
        const int g = s * 64 + lane;
        if (g < mm) {
          float dv = __uint_as_float(k[s]);
          float w_ = 1.f / (sqrtf(fmaxf(dv, 1e-12f)) + 1e-5f);
          sSel[wv][g] = make_uint2(id[s], __float_as_uint(w_));
        }
      }
    }
  }

  // ---- weighted feature gather: lane owns 2 channels ----
  float ax = 0.f, ay = 0.f;
  #pragma unroll 8
  for (int j = 0; j < KNN; ++j) {
    const uint2 pr = sSel[wv][j];     // broadcast LDS read
    const float w = __uint_as_float(pr.y);
    const float2 f2 = *(const float2*)(feat + ((size_t)pr.x << 7) + (lane << 1));
    ax = fmaf(w, f2.x, ax);
    ay = fmaf(w, f2.y, ay);
  }
  *(float2*)(out + ((size_t)gq << 7) + (lane << 1)) = make_float2(ax, ay);
}

// ===================== fallback: R3 brute-force kernel (used if ws too small) =============
#define QPB   4
#define CAPW  56
#define NBLK  (NQ / QPB)
#define PPW   (NPTS / 4)
#define NGRP  (PPW / 256)
#define MAXM  224

__device__ __forceinline__ unsigned key_of(float f) {
  unsigned u = __float_as_uint(f);
  return (u & 0x80000000u) ? ~u : (u | 0x80000000u);
}
__device__ __forceinline__ float val_of(unsigned k) {
  unsigned u = (k & 0x80000000u) ? (k & 0x7fffffffu) : ~k;
  return __uint_as_float(u);
}
__device__ __forceinline__ float rflf(float x) {
  return __int_as_float(__builtin_amdgcn_readfirstlane(__float_as_int(x)));
}
__device__ __forceinline__ int rfli(int x) { return __builtin_amdgcn_readfirstlane(x); }

__global__ __launch_bounds__(256, 8) void ft_knn_fallback(
    const float* __restrict__ qpos, const float* __restrict__ feat,
    const float* __restrict__ pos, float* __restrict__ out) {
  __shared__ uint2 sCand[QPB][4][CAPW];
  __shared__ uint2 sSel[QPB][KNN];
  __shared__ int   sCntW[4][QPB];
  __shared__ float sQ[QPB][4];
  __shared__ float sTau[QPB], sTlo[QPB], sThi[QPB];
  __shared__ int   sAct[QPB], sAny;
  const int tid = threadIdx.x, lane = tid & 63, wv = tid >> 6;
  const int qbase = blockIdx.x * QPB;
  if (tid < QPB) {
    int gq = qbase + tid;
    float x = qpos[gq * 3], y = qpos[gq * 3 + 1], z = qpos[gq * 3 + 2];
    float b = x * x + y * y + z * z;
    sQ[tid][0] = -2.f * x; sQ[tid][1] = -2.f * y; sQ[tid][2] = -2.f * z; sQ[tid][3] = b;
    float mu = fmaxf(sqrtf(b), 0.05f);
    const float target = 110.0f / 32768.0f;
    float lo = 0.f, hi = mu + 8.f;
    for (int i = 0; i < 16; ++i) {
      float r = 0.5f * (lo + hi);
      if (ball_mass(mu, r) < target) lo = r; else hi = r;
    }
    sTau[tid] = hi * hi; sTlo[tid] = 0.f; sThi[tid] = -1.f; sAct[tid] = 1;
  }
  __syncthreads();
  for (int attempt = 0; attempt < 12; ++attempt) {
    float qx[QPB], qy[QPB], qz[QPB], bq[QPB], tq[QPB]; int act[QPB], cnt[QPB];
    #pragma unroll
    for (int q = 0; q < QPB; ++q) {
      qx[q] = rflf(sQ[q][0]); qy[q] = rflf(sQ[q][1]); qz[q] = rflf(sQ[q][2]);
      bq[q] = rflf(sQ[q][3]); act[q] = rfli(sAct[q]);
      float tau = rflf(sTau[q]);
      tq[q] = act[q] ? (tau - bq[q]) : -1e30f; cnt[q] = 0;
    }
    if (act[0] | act[1] | act[2] | act[3]) {
      const int pw = wv * PPW;
      for (int g = 0; g < NGRP; ++g) {
        const int pt = pw + g * 256 + lane * 4;
        const float* bp = pos + (size_t)pt * 3;
        const float4 A = *(const float4*)(bp), B = *(const float4*)(bp + 4), Cc = *(const float4*)(bp + 8);
        const float x0 = A.x, y0 = A.y, z0 = A.z, x1 = A.w, y1 = B.x, z1 = B.y;
        const float x2 = B.z, y2 = B.w, z2 = Cc.x, x3 = Cc.y, y3 = Cc.z, z3 = Cc.w;
        const float n0 = x0*x0+y0*y0+z0*z0, n1 = x1*x1+y1*y1+z1*z1;
        const float n2 = x2*x2+y2*y2+z2*z2, n3 = x3*x3+y3*y3+z3*z3;
        #pragma unroll
        for (int q = 0; q < QPB; ++q) {
          float d0 = fmaf(z0, qz[q], fmaf(y0, qy[q], fmaf(x0, qx[q], n0)));
          float d1 = fmaf(z1, qz[q], fmaf(y1, qy[q], fmaf(x1, qx[q], n1)));
          float d2 = fmaf(z2, qz[q], fmaf(y2, qy[q], fmaf(x2, qx[q], n2)));
          float d3 = fmaf(z3, qz[q], fmaf(y3, qy[q], fmaf(x3, qx[q], n3)));
          const bool h0 = d0 < tq[q], h1 = d1 < tq[q], h2 = d2 < tq[q], h3 = d3 < tq[q];
          const unsigned long long m0 = __ballot(h0), m1 = __ballot(h1), m2 = __ballot(h2), m3 = __ballot(h3);
          if (m0) { int p = cnt[q] + mbcnt64(m0); if (h0 && p < CAPW) sCand[q][wv][p] = make_uint2(key_of(d0 + bq[q]), (unsigned)(pt)); cnt[q] += (int)__popcll(m0); }
          if (m1) { int p = cnt[q] + mbcnt64(m1); if (h1 && p < CAPW) sCand[q][wv][p] = make_uint2(key_of(d1 + bq[q]), (unsigned)(pt + 1)); cnt[q] += (int)__popcll(m1); }
          if (m2) { int p = cnt[q] + mbcnt64(m2); if (h2 && p < CAPW) sCand[q][wv][p] = make_uint2(key_of(d2 + bq[q]), (unsigned)(pt + 2)); cnt[q] += (int)__popcll(m2); }
          if (m3) { int p = cnt[q] + mbcnt64(m3); if (h3 && p < CAPW) sCand[q][wv][p] = make_uint2(key_of(d3 + bq[q]), (unsigned)(pt + 3)); cnt[q] += (int)__popcll(m3); }
        }
      }
    }
    __syncthreads();
    if (lane == 0) {
      #pragma unroll
      for (int q = 0; q < QPB; ++q) { if (act[q]) sCntW[wv][q] = cnt[q]; }
    }
    if (tid == 0) sAny = 0;
    __syncthreads();
    if (tid < QPB && sAct[tid]) {
      int tot = 0, ovf = 0;
      #pragma unroll
      for (int w = 0; w < 4; ++w) { int c = sCntW[w][tid]; ovf |= (c > CAPW); tot += c; }
      if (!ovf && tot >= KNN && tot <= MAXM) sAct[tid] = 0;
      else {
        if (!ovf && tot < KNN) { sTlo[tid] = sTau[tid];
          sTau[tid] = (sThi[tid] < 0.f) ? sTau[tid] * 3.f : 0.5f * (sTau[tid] + sThi[tid]); }
        else { sThi[tid] = sTau[tid]; sTau[tid] = 0.5f * (sTlo[tid] + sTau[tid]); }
        sAny = 1;
      }
    }
    __syncthreads();
    if (!sAny) break;
  }
  {
    const int q = wv;
    const int c0 = rfli(min(sCntW[0][q], CAPW)), c1 = rfli(min(sCntW[1][q], CAPW));
    const int c2 = rfli(min(sCntW[2][q], CAPW)), c3 = rfli(min(sCntW[3][q], CAPW));
    const int P1 = c0, P2 = P1 + c1, P3 = P2 + c2, m = P3 + c3;
    unsigned k[4], id[4];
    #pragma unroll
    for (int s = 0; s < 4; ++s) {
      const int g = s * 64 + lane;
      const int ge1 = g >= P1, ge2 = g >= P2, ge3 = g >= P3;
      const int w = ge1 + ge2 + ge3;
      const int sb = ge3 ? P3 : (ge2 ? P2 : (ge1 ? P1 : 0));
      uint2 kv = make_uint2(0xFFFFFFFFu, 0u);
      if (g < m) kv = sCand[q][w][g - sb];
      k[s] = kv.x; id[s] = kv.y;
    }
    unsigned lo = 0u, hi = 0xFFFFFFFFu;
    for (int it = 0; it < 32; ++it) {
      unsigned mid = lo + ((hi - lo) >> 1);
      int c = (int)(__popcll(__ballot(k[0] <= mid)) + __popcll(__ballot(k[1] <= mid)) +
                    __popcll(__ballot(k[2] <= mid)) + __popcll(__ballot(k[3] <= mid)));
      if (c >= KNN) hi = mid; else lo = mid + 1;
    }
    const unsigned K = lo;
    int fill = 0;
    #pragma unroll
    for (int s = 0; s < 4; ++s) {
      const bool lt = k[s] < K;
      const unsigned long long msk = __ballot(lt);
      if (msk) { const int p = fill + mbcnt64(msk);
        if (lt) { float dv = val_of(k[s]); float w_ = 1.f / (sqrtf(fmaxf(dv, 1e-12f)) + 1e-5f);
                  sSel[q][p] = make_uint2(id[s], __float_as_uint(w_)); }
        fill += (int)__popcll(msk); }
    }
    #pragma unroll
    for (int s = 0; s < 4; ++s) {
      const bool eq = (k[s] == K);
      const unsigned long long msk = __ballot(eq);
      if (msk) { const int p = fill + mbcnt64(msk);
        if (eq && p < KNN) { float dv = val_of(k[s]); float w_ = 1.f / (sqrtf(fmaxf(dv, 1e-12f)) + 1e-5f);
                             sSel[q][p] = make_uint2(id[s], __float_as_uint(w_)); }
        fill += (int)__popcll(msk); }
    }
  }
  {
    const int q = wv, gq = qbase + wv;
    float ax = 0.f, ay = 0.f;
    #pragma unroll 8
    for (int j = 0; j < KNN; ++j) {
      const uint2 pr = sSel[q][j];
      const float w = __uint_as_float(pr.y);
      const float2 f2 = *(const float2*)(feat + ((size_t)pr.x << 7) + (lane << 1));
      ax = fmaf(w, f2.x, ax);
      ay = fmaf(w, f2.y, ay);
    }
    *(float2*)(out + ((size_t)gq << 7) + (lane << 1)) = make_float2(ax, ay);
  }
}

extern "C" void kernel_launch(void* const* d_in, const int* in_sizes, int n_in,
                              void* d_out, int out_size, void* d_ws, size_t ws_size,
                              hipStream_t stream) {
  const float* qpos = (const float*)d_in[0];   // [8192,3]
  const float* feat = (const float*)d_in[1];   // [32768,128]
  const float* pos  = (const float*)d_in[2];   // [32768,3]
  float* out = (float*)d_out;                  // [8192,128]

  if (ws_size >= (size_t)WS_TOTAL * 4) {
    float* wsf = (float*)d_ws;
    int*   wsi = (int*)d_ws;
    int*   cnt   = wsi + WS_CNT;
    int*   start = wsi + WS_START;
    float* tau   = wsf + WS_TAU;
    float* X     = wsf + WS_X;
    float* Y     = wsf + WS_Y;
    float* Z     = wsf + WS_Z;
    int*   I     = wsi + WS_I;
    (void)hipMemsetAsync(cnt, 0, NCELL * sizeof(int), stream);
    k_count_tau<<<dim3(160), dim3(256), 0, stream>>>(qpos, pos, cnt, tau);
    k_scan<<<dim3(1), dim3(256), 0, stream>>>(cnt, start);
    k_scatter<<<dim3(128), dim3(256), 0, stream>>>(pos, cnt, X, Y, Z, I);
    k_main<<<dim3(NQ / 4), dim3(256), 0, stream>>>(qpos, feat, tau, start, X, Y, Z, I, out);
  } else {
    ft_knn_fallback<<<dim3(NBLK), dim3(256), 0, stream>>>(qpos, feat, pos, out);
  }
}